// Round 1
// baseline (281.921 us; speedup 1.0000x reference)
//
#include <hip/hip_runtime.h>

#define THREADS 256
#define GRID 2048

__global__ void zero_ws_kernel(float* ws) {
    ws[0] = 0.0f;
}

__global__ __launch_bounds__(THREADS) void dot_reduce_kernel(
        const float4* __restrict__ a,
        const float4* __restrict__ b,
        float* __restrict__ ws,
        long long n4) {
    long long idx    = (long long)blockIdx.x * THREADS + threadIdx.x;
    long long stride = (long long)gridDim.x * THREADS;

    float acc = 0.0f;
    for (long long i = idx; i < n4; i += stride) {
        float4 x = a[i];
        float4 y = b[i];
        acc = fmaf(x.x, y.x, acc);
        acc = fmaf(x.y, y.y, acc);
        acc = fmaf(x.z, y.z, acc);
        acc = fmaf(x.w, y.w, acc);
    }

    // wave-64 shuffle reduction
    #pragma unroll
    for (int off = 32; off > 0; off >>= 1)
        acc += __shfl_down(acc, off, 64);

    __shared__ float smem[THREADS / 64];
    int lane = threadIdx.x & 63;
    int wave = threadIdx.x >> 6;
    if (lane == 0) smem[wave] = acc;
    __syncthreads();

    if (threadIdx.x == 0) {
        float s = 0.0f;
        #pragma unroll
        for (int w = 0; w < THREADS / 64; ++w) s += smem[w];
        atomicAdd(ws, s);   // device-scope by default on CDNA
    }
}

__global__ void finalize_kernel(const float* __restrict__ ws,
                                float* __restrict__ out,
                                float inv_n) {
    out[0] = 1.0f - ws[0] * inv_n;
}

extern "C" void kernel_launch(void* const* d_in, const int* in_sizes, int n_in,
                              void* d_out, int out_size, void* d_ws, size_t ws_size,
                              hipStream_t stream) {
    const float* feats  = (const float*)d_in[0];
    const float* warped = (const float*)d_in[1];
    float* out = (float*)d_out;
    float* ws  = (float*)d_ws;

    const long long total = (long long)in_sizes[0];   // D*N = 512*65536
    const long long n4 = total / 4;                   // exactly divisible
    const float inv_n = 1.0f / 65536.0f;              // N fixed by the reference

    zero_ws_kernel<<<1, 1, 0, stream>>>(ws);
    dot_reduce_kernel<<<GRID, THREADS, 0, stream>>>(
        (const float4*)feats, (const float4*)warped, ws, n4);
    finalize_kernel<<<1, 1, 0, stream>>>(ws, out, inv_n);
}

// Round 2
// 276.754 us; speedup vs baseline: 1.0187x; 1.0187x over previous
//
#include <hip/hip_runtime.h>

#define THREADS 256
#define VPT 4   // float4s per thread per input array

__global__ __launch_bounds__(THREADS) void dot_partial_kernel(
        const float4* __restrict__ a,
        const float4* __restrict__ b,
        float* __restrict__ partial) {
    const int base = blockIdx.x * (THREADS * VPT) + threadIdx.x;

    // Issue all 8 loads before any use — maximize loads in flight.
    float4 xa[VPT], xb[VPT];
    #pragma unroll
    for (int j = 0; j < VPT; ++j) xa[j] = a[base + j * THREADS];
    #pragma unroll
    for (int j = 0; j < VPT; ++j) xb[j] = b[base + j * THREADS];

    float acc[VPT];
    #pragma unroll
    for (int j = 0; j < VPT; ++j) {
        acc[j] = xa[j].x * xb[j].x;
        acc[j] = fmaf(xa[j].y, xb[j].y, acc[j]);
        acc[j] = fmaf(xa[j].z, xb[j].z, acc[j]);
        acc[j] = fmaf(xa[j].w, xb[j].w, acc[j]);
    }
    float s = (acc[0] + acc[1]) + (acc[2] + acc[3]);

    // wave-64 shuffle reduction
    #pragma unroll
    for (int off = 32; off > 0; off >>= 1)
        s += __shfl_down(s, off, 64);

    __shared__ float smem[THREADS / 64];
    int lane = threadIdx.x & 63;
    int wave = threadIdx.x >> 6;
    if (lane == 0) smem[wave] = s;
    __syncthreads();

    if (threadIdx.x == 0) {
        float t = 0.f;
        #pragma unroll
        for (int w = 0; w < THREADS / 64; ++w) t += smem[w];
        partial[blockIdx.x] = t;
    }
}

__global__ __launch_bounds__(THREADS) void final_reduce_kernel(
        const float* __restrict__ partial,
        float* __restrict__ out,
        int np, float inv_n) {
    float s = 0.f;
    for (int i = threadIdx.x; i < np; i += THREADS) s += partial[i];

    #pragma unroll
    for (int off = 32; off > 0; off >>= 1)
        s += __shfl_down(s, off, 64);

    __shared__ float smem[THREADS / 64];
    int lane = threadIdx.x & 63;
    int wave = threadIdx.x >> 6;
    if (lane == 0) smem[wave] = s;
    __syncthreads();

    if (threadIdx.x == 0) {
        float t = 0.f;
        #pragma unroll
        for (int w = 0; w < THREADS / 64; ++w) t += smem[w];
        out[0] = 1.0f - t * inv_n;
    }
}

extern "C" void kernel_launch(void* const* d_in, const int* in_sizes, int n_in,
                              void* d_out, int out_size, void* d_ws, size_t ws_size,
                              hipStream_t stream) {
    const float* feats  = (const float*)d_in[0];
    const float* warped = (const float*)d_in[1];
    float* out = (float*)d_out;
    float* ws  = (float*)d_ws;

    const long long total = (long long)in_sizes[0];      // 512*65536 = 33554432
    const int n4 = (int)(total / 4);                     // 8388608
    const int blocks = n4 / (THREADS * VPT);             // 8192, exact
    const float inv_n = 1.0f / 65536.0f;                 // N fixed by reference

    dot_partial_kernel<<<blocks, THREADS, 0, stream>>>(
        (const float4*)feats, (const float4*)warped, ws);
    final_reduce_kernel<<<1, THREADS, 0, stream>>>(ws, out, blocks, inv_n);
}

// Round 3
// 274.151 us; speedup vs baseline: 1.0283x; 1.0095x over previous
//
#include <hip/hip_runtime.h>

#define THREADS 256
#define BLOCKS  2048
#define VPT     4   // float4s per chunk per thread
#define CHUNKS  4   // chunks per block
// total float4 per array = BLOCKS * CHUNKS * THREADS * VPT = 8,388,608 == (512*65536)/4

__global__ __launch_bounds__(THREADS) void dot_partial_kernel(
        const float4* __restrict__ a,
        const float4* __restrict__ b,
        float* __restrict__ partial) {
    const int tile  = CHUNKS * THREADS * VPT;          // 4096 float4 per block
    const int base0 = blockIdx.x * tile + threadIdx.x;

    float4 xa[2][VPT], xb[2][VPT];

    // prefetch chunk 0
    #pragma unroll
    for (int j = 0; j < VPT; ++j) {
        xa[0][j] = a[base0 + j * THREADS];
        xb[0][j] = b[base0 + j * THREADS];
    }

    float acc[VPT] = {0.f, 0.f, 0.f, 0.f};

    #pragma unroll
    for (int c = 0; c < CHUNKS; ++c) {
        const int cur = c & 1;
        const int nxt = cur ^ 1;
        if (c + 1 < CHUNKS) {
            const int baseN = base0 + (c + 1) * THREADS * VPT;
            #pragma unroll
            for (int j = 0; j < VPT; ++j) {
                xa[nxt][j] = a[baseN + j * THREADS];
                xb[nxt][j] = b[baseN + j * THREADS];
            }
        }
        #pragma unroll
        for (int j = 0; j < VPT; ++j) {
            acc[j] = fmaf(xa[cur][j].x, xb[cur][j].x, acc[j]);
            acc[j] = fmaf(xa[cur][j].y, xb[cur][j].y, acc[j]);
            acc[j] = fmaf(xa[cur][j].z, xb[cur][j].z, acc[j]);
            acc[j] = fmaf(xa[cur][j].w, xb[cur][j].w, acc[j]);
        }
    }
    float s = (acc[0] + acc[1]) + (acc[2] + acc[3]);

    // wave-64 shuffle reduction
    #pragma unroll
    for (int off = 32; off > 0; off >>= 1)
        s += __shfl_down(s, off, 64);

    __shared__ float smem[THREADS / 64];
    const int lane = threadIdx.x & 63;
    const int wave = threadIdx.x >> 6;
    if (lane == 0) smem[wave] = s;
    __syncthreads();

    if (threadIdx.x == 0) {
        float t = 0.f;
        #pragma unroll
        for (int w = 0; w < THREADS / 64; ++w) t += smem[w];
        partial[blockIdx.x] = t;
    }
}

__global__ __launch_bounds__(THREADS) void final_reduce_kernel(
        const float* __restrict__ partial,
        float* __restrict__ out,
        int np, float inv_n) {
    float s = 0.f;
    for (int i = threadIdx.x; i < np; i += THREADS) s += partial[i];

    #pragma unroll
    for (int off = 32; off > 0; off >>= 1)
        s += __shfl_down(s, off, 64);

    __shared__ float smem[THREADS / 64];
    const int lane = threadIdx.x & 63;
    const int wave = threadIdx.x >> 6;
    if (lane == 0) smem[wave] = s;
    __syncthreads();

    if (threadIdx.x == 0) {
        float t = 0.f;
        #pragma unroll
        for (int w = 0; w < THREADS / 64; ++w) t += smem[w];
        out[0] = 1.0f - t * inv_n;
    }
}

extern "C" void kernel_launch(void* const* d_in, const int* in_sizes, int n_in,
                              void* d_out, int out_size, void* d_ws, size_t ws_size,
                              hipStream_t stream) {
    const float* feats  = (const float*)d_in[0];
    const float* warped = (const float*)d_in[1];
    float* out = (float*)d_out;
    float* ws  = (float*)d_ws;

    const float inv_n = 1.0f / 65536.0f;   // N fixed by the reference

    dot_partial_kernel<<<BLOCKS, THREADS, 0, stream>>>(
        (const float4*)feats, (const float4*)warped, ws);
    final_reduce_kernel<<<1, THREADS, 0, stream>>>(ws, out, BLOCKS, inv_n);
}

// Round 4
// 248.614 us; speedup vs baseline: 1.1340x; 1.1027x over previous
//
#include <hip/hip_runtime.h>

#define THREADS 512
#define BLOCKS  1024   // 512*1024 threads = 8192 waves = 32 waves/CU: full residency
#define ITERS   16     // 524288 threads * 16 = 8,388,608 float4 = (512*65536)/4 exactly
#define UNROLL  4

typedef float f32x4 __attribute__((ext_vector_type(4)));

__global__ __launch_bounds__(THREADS) void dot_partial_kernel(
        const f32x4* __restrict__ a,
        const f32x4* __restrict__ b,
        float* __restrict__ partial) {
    const int tid    = blockIdx.x * THREADS + threadIdx.x;
    const int stride = THREADS * BLOCKS;

    f32x4 acc0 = (f32x4)0.f, acc1 = (f32x4)0.f, acc2 = (f32x4)0.f, acc3 = (f32x4)0.f;

    #pragma unroll
    for (int i = 0; i < ITERS; i += UNROLL) {
        long long i0 = (long long)(i + 0) * stride + tid;
        long long i1 = (long long)(i + 1) * stride + tid;
        long long i2 = (long long)(i + 2) * stride + tid;
        long long i3 = (long long)(i + 3) * stride + tid;
        f32x4 a0 = __builtin_nontemporal_load(a + i0);
        f32x4 b0 = __builtin_nontemporal_load(b + i0);
        f32x4 a1 = __builtin_nontemporal_load(a + i1);
        f32x4 b1 = __builtin_nontemporal_load(b + i1);
        f32x4 a2 = __builtin_nontemporal_load(a + i2);
        f32x4 b2 = __builtin_nontemporal_load(b + i2);
        f32x4 a3 = __builtin_nontemporal_load(a + i3);
        f32x4 b3 = __builtin_nontemporal_load(b + i3);
        acc0 += a0 * b0;
        acc1 += a1 * b1;
        acc2 += a2 * b2;
        acc3 += a3 * b3;
    }

    f32x4 accv = (acc0 + acc1) + (acc2 + acc3);
    float s = (accv.x + accv.y) + (accv.z + accv.w);

    // wave-64 shuffle reduction
    #pragma unroll
    for (int off = 32; off > 0; off >>= 1)
        s += __shfl_down(s, off, 64);

    __shared__ float smem[THREADS / 64];
    const int lane = threadIdx.x & 63;
    const int wave = threadIdx.x >> 6;
    if (lane == 0) smem[wave] = s;
    __syncthreads();

    if (threadIdx.x == 0) {
        float t = 0.f;
        #pragma unroll
        for (int w = 0; w < THREADS / 64; ++w) t += smem[w];
        partial[blockIdx.x] = t;
    }
}

__global__ __launch_bounds__(256) void final_reduce_kernel(
        const float* __restrict__ partial,
        float* __restrict__ out,
        int np, float inv_n) {
    float s = 0.f;
    for (int i = threadIdx.x; i < np; i += 256) s += partial[i];

    #pragma unroll
    for (int off = 32; off > 0; off >>= 1)
        s += __shfl_down(s, off, 64);

    __shared__ float smem[4];
    const int lane = threadIdx.x & 63;
    const int wave = threadIdx.x >> 6;
    if (lane == 0) smem[wave] = s;
    __syncthreads();

    if (threadIdx.x == 0) {
        float t = 0.f;
        #pragma unroll
        for (int w = 0; w < 4; ++w) t += smem[w];
        out[0] = 1.0f - t * inv_n;
    }
}

extern "C" void kernel_launch(void* const* d_in, const int* in_sizes, int n_in,
                              void* d_out, int out_size, void* d_ws, size_t ws_size,
                              hipStream_t stream) {
    const float* feats  = (const float*)d_in[0];
    const float* warped = (const float*)d_in[1];
    float* out = (float*)d_out;
    float* ws  = (float*)d_ws;

    const float inv_n = 1.0f / 65536.0f;   // N fixed by the reference

    dot_partial_kernel<<<BLOCKS, THREADS, 0, stream>>>(
        (const f32x4*)feats, (const f32x4*)warped, ws);
    final_reduce_kernel<<<1, 256, 0, stream>>>(ws, out, BLOCKS, inv_n);
}

// Round 5
// 247.384 us; speedup vs baseline: 1.1396x; 1.0050x over previous
//
#include <hip/hip_runtime.h>

#define THREADS 512
#define BLOCKS  1024   // 1024*512 = 524288 threads = 8192 waves = 32/CU: full residency
#define ITERS   16     // per-block tile: 16*512 float4 = 8192 float4 = 128 KB per array
#define UNROLL  4

typedef float f32x4 __attribute__((ext_vector_type(4)));

__global__ __launch_bounds__(THREADS) void dot_partial_kernel(
        const f32x4* __restrict__ a,
        const f32x4* __restrict__ b,
        float* __restrict__ partial) {
    // Block-contiguous tile: block owns [blockIdx*8192, (blockIdx+1)*8192) float4s.
    const int base = blockIdx.x * (ITERS * THREADS) + threadIdx.x;

    f32x4 acc0 = (f32x4)0.f, acc1 = (f32x4)0.f, acc2 = (f32x4)0.f, acc3 = (f32x4)0.f;

    #pragma unroll
    for (int i = 0; i < ITERS; i += UNROLL) {
        const int i0 = base + (i + 0) * THREADS;
        const int i1 = base + (i + 1) * THREADS;
        const int i2 = base + (i + 2) * THREADS;
        const int i3 = base + (i + 3) * THREADS;
        f32x4 a0 = __builtin_nontemporal_load(a + i0);
        f32x4 b0 = __builtin_nontemporal_load(b + i0);
        f32x4 a1 = __builtin_nontemporal_load(a + i1);
        f32x4 b1 = __builtin_nontemporal_load(b + i1);
        f32x4 a2 = __builtin_nontemporal_load(a + i2);
        f32x4 b2 = __builtin_nontemporal_load(b + i2);
        f32x4 a3 = __builtin_nontemporal_load(a + i3);
        f32x4 b3 = __builtin_nontemporal_load(b + i3);
        acc0 += a0 * b0;
        acc1 += a1 * b1;
        acc2 += a2 * b2;
        acc3 += a3 * b3;
    }

    f32x4 accv = (acc0 + acc1) + (acc2 + acc3);
    float s = (accv.x + accv.y) + (accv.z + accv.w);

    // wave-64 shuffle reduction
    #pragma unroll
    for (int off = 32; off > 0; off >>= 1)
        s += __shfl_down(s, off, 64);

    __shared__ float smem[THREADS / 64];
    const int lane = threadIdx.x & 63;
    const int wave = threadIdx.x >> 6;
    if (lane == 0) smem[wave] = s;
    __syncthreads();

    if (threadIdx.x == 0) {
        float t = 0.f;
        #pragma unroll
        for (int w = 0; w < THREADS / 64; ++w) t += smem[w];
        partial[blockIdx.x] = t;
    }
}

__global__ __launch_bounds__(256) void final_reduce_kernel(
        const float* __restrict__ partial,
        float* __restrict__ out,
        int np, float inv_n) {
    float s = 0.f;
    for (int i = threadIdx.x; i < np; i += 256) s += partial[i];

    #pragma unroll
    for (int off = 32; off > 0; off >>= 1)
        s += __shfl_down(s, off, 64);

    __shared__ float smem[4];
    const int lane = threadIdx.x & 63;
    const int wave = threadIdx.x >> 6;
    if (lane == 0) smem[wave] = s;
    __syncthreads();

    if (threadIdx.x == 0) {
        float t = 0.f;
        #pragma unroll
        for (int w = 0; w < 4; ++w) t += smem[w];
        out[0] = 1.0f - t * inv_n;
    }
}

extern "C" void kernel_launch(void* const* d_in, const int* in_sizes, int n_in,
                              void* d_out, int out_size, void* d_ws, size_t ws_size,
                              hipStream_t stream) {
    const float* feats  = (const float*)d_in[0];
    const float* warped = (const float*)d_in[1];
    float* out = (float*)d_out;
    float* ws  = (float*)d_ws;

    const float inv_n = 1.0f / 65536.0f;   // N fixed by the reference

    dot_partial_kernel<<<BLOCKS, THREADS, 0, stream>>>(
        (const f32x4*)feats, (const f32x4*)warped, ws);
    final_reduce_kernel<<<1, 256, 0, stream>>>(ws, out, BLOCKS, inv_n);
}